// Round 1
// baseline (655.052 us; speedup 1.0000x reference)
//
#include <hip/hip_runtime.h>

typedef __attribute__((ext_vector_type(8))) short bf16x8;
typedef __attribute__((ext_vector_type(4))) float f32x4;
typedef __attribute__((ext_vector_type(4))) short short4v;
typedef __attribute__((ext_vector_type(8))) short short8v;
typedef __attribute__((ext_vector_type(4))) float float4v;

#define DEV static __device__ __forceinline__

DEV short f2bf(float f) {
  unsigned u = __builtin_bit_cast(unsigned, f);
  u = (u + 0x7fffu + ((u >> 16) & 1u)) >> 16;
  return (short)u;
}
DEV float bf2f(short s) {
  unsigned u = ((unsigned)(unsigned short)s) << 16;
  return __builtin_bit_cast(float, u);
}

DEV void gload_lds16(const void* g, void* l) {
  __builtin_amdgcn_global_load_lds((const __attribute__((address_space(1))) void*)g,
                                   (__attribute__((address_space(3))) void*)l, 16, 0, 0);
}

// ---------------- LayerNorm: f32 [rows][2048] -> bf16 ----------------
__global__ __launch_bounds__(256) void ln_kernel(const float* __restrict__ x,
                                                 const float* __restrict__ w,
                                                 const float* __restrict__ b,
                                                 short* __restrict__ out) {
  const int C = 2048;
  const int row = blockIdx.x;
  const int tid = threadIdx.x;
  const float* xr = x + (size_t)row * C;
  float xv[8];
  *(float4v*)(xv) = *(const float4v*)(xr + tid * 8);
  *(float4v*)(xv + 4) = *(const float4v*)(xr + tid * 8 + 4);
  float s = 0.f, ss = 0.f;
#pragma unroll
  for (int i = 0; i < 8; ++i) { s += xv[i]; ss += xv[i] * xv[i]; }
#pragma unroll
  for (int d = 1; d < 64; d <<= 1) { s += __shfl_xor(s, d); ss += __shfl_xor(ss, d); }
  __shared__ float red[8];
  const int lane = tid & 63, wv = tid >> 6;
  if (lane == 0) { red[wv] = s; red[4 + wv] = ss; }
  __syncthreads();
  s = red[0] + red[1] + red[2] + red[3];
  ss = red[4] + red[5] + red[6] + red[7];
  const float mean = s * (1.f / 2048.f);
  const float var = ss * (1.f / 2048.f) - mean * mean;
  const float rs = rsqrtf(var + 1e-5f);
  float wv8[8], bv8[8];
  *(float4v*)(wv8) = *(const float4v*)(w + tid * 8);
  *(float4v*)(wv8 + 4) = *(const float4v*)(w + tid * 8 + 4);
  *(float4v*)(bv8) = *(const float4v*)(b + tid * 8);
  *(float4v*)(bv8 + 4) = *(const float4v*)(b + tid * 8 + 4);
  short8v o;
#pragma unroll
  for (int i = 0; i < 8; ++i) o[i] = f2bf((xv[i] - mean) * rs * wv8[i] + bv8[i]);
  *(short8v*)(out + (size_t)row * C + tid * 8) = o;
}

// ---------------- GEMM: C[M][N] = A[M][K](bf16) * Bw[N][K](f32)^T ----------------
// EPI: 0 = store bf16, 1 = store f32 (resid + acc), 2 = exact GELU -> bf16
template <int EPI>
__global__ __launch_bounds__(256) void gemm_bt(const short* __restrict__ A,
                                               const float* __restrict__ Bw,
                                               void* __restrict__ Cout,
                                               const float* __restrict__ resid,
                                               int N, int K) {
  __shared__ short As[128 * 64];
  __shared__ short Bs[128 * 64];
  const int tid = threadIdx.x;
  const int lane = tid & 63;
  const int w = tid >> 6;
  const int wr = w >> 1, wc = w & 1;
  const int m0 = blockIdx.y * 128;
  const int n0 = blockIdx.x * 128;

  f32x4 acc[4][4] = {};

  const int sr = lane >> 3;
  const int sc = (lane & 7) * 8;
  const int l15 = lane & 15;
  const int lg = lane >> 4;

  for (int k0 = 0; k0 < K; k0 += 64) {
    __syncthreads();
#pragma unroll
    for (int j = 0; j < 4; ++j) {
      const int r0 = (j * 4 + w) * 8;
      gload_lds16(A + (size_t)(m0 + r0 + sr) * K + k0 + sc, As + r0 * 64);
    }
#pragma unroll
    for (int j = 0; j < 8; ++j) {
      const int f = j * 256 + tid;
      const int row = f >> 4;
      const int c4 = (f & 15) * 4;
      float4v v = *(const float4v*)(Bw + (size_t)(n0 + row) * K + k0 + c4);
      short4v sv;
      sv.x = f2bf(v.x); sv.y = f2bf(v.y); sv.z = f2bf(v.z); sv.w = f2bf(v.w);
      *(short4v*)(Bs + row * 64 + c4) = sv;
    }
    __syncthreads();
#pragma unroll
    for (int kk = 0; kk < 64; kk += 32) {
      bf16x8 af[4], bfr[4];
#pragma unroll
      for (int m = 0; m < 4; ++m)
        af[m] = *(const bf16x8*)(As + (wr * 64 + m * 16 + l15) * 64 + kk + lg * 8);
#pragma unroll
      for (int n = 0; n < 4; ++n)
        bfr[n] = *(const bf16x8*)(Bs + (wc * 64 + n * 16 + l15) * 64 + kk + lg * 8);
#pragma unroll
      for (int m = 0; m < 4; ++m)
#pragma unroll
        for (int n = 0; n < 4; ++n)
          acc[m][n] = __builtin_amdgcn_mfma_f32_16x16x32_bf16(af[m], bfr[n], acc[m][n], 0, 0, 0);
    }
  }

  const int rl = lg * 4;
#pragma unroll
  for (int m = 0; m < 4; ++m) {
#pragma unroll
    for (int n = 0; n < 4; ++n) {
#pragma unroll
      for (int r = 0; r < 4; ++r) {
        const size_t idx = (size_t)(m0 + wr * 64 + m * 16 + rl + r) * N + (n0 + wc * 64 + n * 16 + l15);
        const float v = acc[m][n][r];
        if (EPI == 0) {
          ((short*)Cout)[idx] = f2bf(v);
        } else if (EPI == 1) {
          ((float*)Cout)[idx] = resid[idx] + v;
        } else {
          const float gl = 0.5f * v * (1.f + erff(v * 0.70710678118f));
          ((short*)Cout)[idx] = f2bf(gl);
        }
      }
    }
  }
}

// ---------------- RoPE + [B,T,3,H,D] -> 3x [B,H,T,D] ----------------
__global__ __launch_bounds__(256) void rope_kernel(const short* __restrict__ qkv,
                                                   short* __restrict__ qo,
                                                   short* __restrict__ ko,
                                                   short* __restrict__ vo,
                                                   const int* __restrict__ offset) {
  const int T = 1024, H = 32;
  const int g = blockIdx.x * 256 + threadIdx.x;
  const int j = g & 31;
  const int h = (g >> 5) & 31;
  const int t = (g >> 10) & 1023;
  const int b = g >> 20;
  const size_t inb = (size_t)(b * T + t) * 6144 + h * 64 + 2 * j;
  const size_t outb = (size_t)((b * H + h) * T + t) * 64 + 2 * j;
  const int pos = offset[b] + t;
  // inv_freq = 10000^(-j/32) = exp2(-log2(10000)*j/32)
  const float ang = (float)pos * __builtin_exp2f(-13.287712379549449f * (float)j * (1.f / 32.f));
  float sn, c;
  __sincosf(ang, &sn, &c);
  const float qr = bf2f(qkv[inb]), qi = bf2f(qkv[inb + 1]);
  qo[outb] = f2bf(qr * c - qi * sn);
  qo[outb + 1] = f2bf(qr * sn + qi * c);
  const float kr = bf2f(qkv[inb + 2048]), ki = bf2f(qkv[inb + 2048 + 1]);
  ko[outb] = f2bf(kr * c - ki * sn);
  ko[outb + 1] = f2bf(kr * sn + ki * c);
  vo[outb] = qkv[inb + 4096];
  vo[outb + 1] = qkv[inb + 4096 + 1];
}

// ---------------- Flash attention, sliding-window causal ----------------
__global__ __launch_bounds__(256) void attn_kernel(const short* __restrict__ qb,
                                                   const short* __restrict__ kb,
                                                   const short* __restrict__ vb,
                                                   short* __restrict__ o,
                                                   const int* __restrict__ offset,
                                                   const int* __restrict__ end_offset,
                                                   const int* __restrict__ ctxp) {
  const int T = 1024;
  __shared__ short Ks[64 * 64];
  __shared__ short Vt[64 * 64];
  __shared__ short Ps[4][16 * 64];
  const int tid = threadIdx.x;
  const int lane = tid & 63;
  const int w = tid >> 6;
  const int blk = blockIdx.x;
  const int qt = blk & 15;
  const int bh = blk >> 4;
  const int b = bh >> 5;
  const int h = bh & 31;
  const int q0 = qt * 64;
  const int offq = offset[b];
  const int offk = end_offset[b];
  const int W = ctxp[0];
  const int odelta = offq - offk;

  const short* qp = qb + (size_t)bh * T * 64;
  const short* kp = kb + (size_t)bh * T * 64;
  const short* vp = vb + (size_t)bh * T * 64;

  const int l15 = lane & 15;
  const int lg = lane >> 4;

  bf16x8 qf[2];
  {
    const int qrow = q0 + w * 16 + l15;
    qf[0] = *(const bf16x8*)(qp + (size_t)qrow * 64 + lg * 8);
    qf[1] = *(const bf16x8*)(qp + (size_t)qrow * 64 + 32 + lg * 8);
  }

  f32x4 oacc[4] = {};
  float mrow[4] = {-1e30f, -1e30f, -1e30f, -1e30f};
  float ssum[4] = {0.f, 0.f, 0.f, 0.f};

  int kv_lo = q0 + odelta - (W - 1);
  if (kv_lo < 0) kv_lo = 0;
  int kv_hi = q0 + 63 + odelta;
  if (kv_hi > T - 1) kv_hi = T - 1;

  for (int t0 = (kv_lo & ~63); t0 <= kv_hi; t0 += 64) {
    __syncthreads();
#pragma unroll
    for (int j = 0; j < 2; ++j) {
      const int r0 = (j * 4 + w) * 8;
      gload_lds16(kp + (size_t)(t0 + r0 + (lane >> 3)) * 64 + (lane & 7) * 8, Ks + r0 * 64);
    }
#pragma unroll
    for (int j = 0; j < 2; ++j) {
      const int kv = (tid >> 3) + j * 32;
      const int d0 = (tid & 7) * 8;
      bf16x8 vv = *(const bf16x8*)(vp + (size_t)(t0 + kv) * 64 + d0);
#pragma unroll
      for (int i = 0; i < 8; ++i) Vt[(d0 + i) * 64 + kv] = vv[i];
    }
    __syncthreads();

    f32x4 s[4] = {};
#pragma unroll
    for (int n = 0; n < 4; ++n) {
      bf16x8 k0f = *(const bf16x8*)(Ks + (n * 16 + l15) * 64 + lg * 8);
      bf16x8 k1f = *(const bf16x8*)(Ks + (n * 16 + l15) * 64 + 32 + lg * 8);
      s[n] = __builtin_amdgcn_mfma_f32_16x16x32_bf16(qf[0], k0f, s[n], 0, 0, 0);
      s[n] = __builtin_amdgcn_mfma_f32_16x16x32_bf16(qf[1], k1f, s[n], 0, 0, 0);
    }

#pragma unroll
    for (int r = 0; r < 4; ++r) {
      const int tq = q0 + w * 16 + lg * 4 + r;
      float sv[4];
      float mx = -1e30f;
#pragma unroll
      for (int n = 0; n < 4; ++n) {
        const int tk = t0 + n * 16 + l15;
        const int dd = tq + odelta - tk;
        const bool valid = (dd >= 0) && (dd < W);
        sv[n] = valid ? s[n][r] * 0.125f : -1e30f;
        mx = fmaxf(mx, sv[n]);
      }
      mx = fmaxf(mx, __shfl_xor(mx, 1));
      mx = fmaxf(mx, __shfl_xor(mx, 2));
      mx = fmaxf(mx, __shfl_xor(mx, 4));
      mx = fmaxf(mx, __shfl_xor(mx, 8));
      const float mnew = fmaxf(mrow[r], mx);
      const float sf = __expf(mrow[r] - mnew);
      mrow[r] = mnew;
      float ls = 0.f;
#pragma unroll
      for (int n = 0; n < 4; ++n) {
        const float p = (sv[n] > -0.5e30f) ? __expf(sv[n] - mnew) : 0.f;
        ls += p;
        Ps[w][(lg * 4 + r) * 64 + n * 16 + l15] = f2bf(p);
      }
      ls += __shfl_xor(ls, 1);
      ls += __shfl_xor(ls, 2);
      ls += __shfl_xor(ls, 4);
      ls += __shfl_xor(ls, 8);
      ssum[r] = ssum[r] * sf + ls;
#pragma unroll
      for (int n = 0; n < 4; ++n) oacc[n][r] *= sf;
    }

#pragma unroll
    for (int ks = 0; ks < 2; ++ks) {
      bf16x8 pa = *(const bf16x8*)(&Ps[w][l15 * 64 + ks * 32 + lg * 8]);
#pragma unroll
      for (int n = 0; n < 4; ++n) {
        bf16x8 vf = *(const bf16x8*)(Vt + (n * 16 + l15) * 64 + ks * 32 + lg * 8);
        oacc[n] = __builtin_amdgcn_mfma_f32_16x16x32_bf16(pa, vf, oacc[n], 0, 0, 0);
      }
    }
  }

#pragma unroll
  for (int n = 0; n < 4; ++n) {
#pragma unroll
    for (int r = 0; r < 4; ++r) {
      const int tq = q0 + w * 16 + lg * 4 + r;
      const float val = oacc[n][r] / ssum[r];
      o[(size_t)(b * T + tq) * 2048 + h * 64 + n * 16 + l15] = f2bf(val);
    }
  }
}

extern "C" void kernel_launch(void* const* d_in, const int* in_sizes, int n_in,
                              void* d_out, int out_size, void* d_ws, size_t ws_size,
                              hipStream_t stream) {
  (void)in_sizes; (void)n_in; (void)out_size; (void)ws_size;
  const float* x          = (const float*)d_in[0];
  const float* in_proj_w  = (const float*)d_in[2];
  const float* out_proj_w = (const float*)d_in[3];
  const float* ln1_w      = (const float*)d_in[4];
  const float* ln1_b      = (const float*)d_in[5];
  const float* ln2_w      = (const float*)d_in[6];
  const float* ln2_b      = (const float*)d_in[7];
  const float* lin1_w     = (const float*)d_in[8];
  const float* lin2_w     = (const float*)d_in[9];
  const int* offset       = (const int*)d_in[10];
  const int* end_offset   = (const int*)d_in[11];
  const int* ctx          = (const int*)d_in[12];
  float* out = (float*)d_out;

  char* ws = (char*)d_ws;
  float* x1  = (float*)ws;                    // 16 MB  f32 [2048][2048]
  short* hbuf = (short*)(ws + 16777216);      // 8 MB   bf16 (h -> o -> h2)
  short* qkv  = (short*)(ws + 25165824);      // 24 MB  bf16 [2048][6144]
  short* qr   = (short*)(ws + 50331648);      // 8 MB   bf16 [B,H,T,D]
  short* kr   = (short*)(ws + 58720256);      // 8 MB
  short* vr   = (short*)(ws + 67108864);      // 8 MB
  short* g    = qkv;                          // 32 MB overlay (qkv+qr region, both dead)

  // 1. LN1: x -> h(bf16)
  ln_kernel<<<2048, 256, 0, stream>>>(x, ln1_w, ln1_b, hbuf);
  // 2. QKV = h @ in_proj_w^T
  gemm_bt<0><<<dim3(48, 16), 256, 0, stream>>>(hbuf, in_proj_w, qkv, nullptr, 6144, 2048);
  // 3. RoPE + rearrange to [B,H,T,D]
  rope_kernel<<<8192, 256, 0, stream>>>(qkv, qr, kr, vr, offset);
  // 4. Attention -> o (reuses hbuf) in [B,T,H*D] layout
  attn_kernel<<<1024, 256, 0, stream>>>(qr, kr, vr, hbuf, offset, end_offset, ctx);
  // 5. x1 = x + o @ out_proj_w^T
  gemm_bt<1><<<dim3(16, 16), 256, 0, stream>>>(hbuf, out_proj_w, x1, x, 2048, 2048);
  // 6. LN2: x1 -> h2 (reuses hbuf)
  ln_kernel<<<2048, 256, 0, stream>>>(x1, ln2_w, ln2_b, hbuf);
  // 7. g = gelu(h2 @ lin1_w^T)
  gemm_bt<2><<<dim3(64, 16), 256, 0, stream>>>(hbuf, lin1_w, g, nullptr, 8192, 2048);
  // 8. out = x1 + g @ lin2_w^T
  gemm_bt<1><<<dim3(16, 16), 256, 0, stream>>>(g, lin2_w, out, x1, 2048, 8192);
}

// Round 2
// 554.265 us; speedup vs baseline: 1.1818x; 1.1818x over previous
//
#include <hip/hip_runtime.h>

typedef __attribute__((ext_vector_type(8))) short bf16x8;
typedef __attribute__((ext_vector_type(4))) float f32x4;
typedef __attribute__((ext_vector_type(8))) short short8v;
typedef __attribute__((ext_vector_type(4))) float float4v;

#define DEV static __device__ __forceinline__

DEV short f2bf(float f) {
  unsigned u = __builtin_bit_cast(unsigned, f);
  u = (u + 0x7fffu + ((u >> 16) & 1u)) >> 16;
  return (short)u;
}
DEV float bf2f(short s) {
  unsigned u = ((unsigned)(unsigned short)s) << 16;
  return __builtin_bit_cast(float, u);
}

DEV void gload_lds16(const void* g, void* l) {
  __builtin_amdgcn_global_load_lds((const __attribute__((address_space(1))) void*)g,
                                   (__attribute__((address_space(3))) void*)l, 16, 0, 0);
}

// ---------------- f32 -> bf16 convert (8 elems/thread, grid-stride) ----------------
__global__ __launch_bounds__(256) void cvt_kernel(const float* __restrict__ src,
                                                  short* __restrict__ dst, int n8) {
  int i = blockIdx.x * 256 + threadIdx.x;
  const int stride = gridDim.x * 256;
  for (; i < n8; i += stride) {
    float4v a = ((const float4v*)src)[i * 2];
    float4v b = ((const float4v*)src)[i * 2 + 1];
    short8v o;
    o[0] = f2bf(a.x); o[1] = f2bf(a.y); o[2] = f2bf(a.z); o[3] = f2bf(a.w);
    o[4] = f2bf(b.x); o[5] = f2bf(b.y); o[6] = f2bf(b.z); o[7] = f2bf(b.w);
    ((short8v*)dst)[i] = o;
  }
}

// ---------------- LayerNorm: f32 [rows][2048] -> bf16 ----------------
__global__ __launch_bounds__(256) void ln_kernel(const float* __restrict__ x,
                                                 const float* __restrict__ w,
                                                 const float* __restrict__ b,
                                                 short* __restrict__ out) {
  const int C = 2048;
  const int row = blockIdx.x;
  const int tid = threadIdx.x;
  const float* xr = x + (size_t)row * C;
  float xv[8];
  *(float4v*)(xv) = *(const float4v*)(xr + tid * 8);
  *(float4v*)(xv + 4) = *(const float4v*)(xr + tid * 8 + 4);
  float s = 0.f, ss = 0.f;
#pragma unroll
  for (int i = 0; i < 8; ++i) { s += xv[i]; ss += xv[i] * xv[i]; }
#pragma unroll
  for (int d = 1; d < 64; d <<= 1) { s += __shfl_xor(s, d); ss += __shfl_xor(ss, d); }
  __shared__ float red[8];
  const int lane = tid & 63, wv = tid >> 6;
  if (lane == 0) { red[wv] = s; red[4 + wv] = ss; }
  __syncthreads();
  s = red[0] + red[1] + red[2] + red[3];
  ss = red[4] + red[5] + red[6] + red[7];
  const float mean = s * (1.f / 2048.f);
  const float var = ss * (1.f / 2048.f) - mean * mean;
  const float rs = rsqrtf(var + 1e-5f);
  float wv8[8], bv8[8];
  *(float4v*)(wv8) = *(const float4v*)(w + tid * 8);
  *(float4v*)(wv8 + 4) = *(const float4v*)(w + tid * 8 + 4);
  *(float4v*)(bv8) = *(const float4v*)(b + tid * 8);
  *(float4v*)(bv8 + 4) = *(const float4v*)(b + tid * 8 + 4);
  short8v o;
#pragma unroll
  for (int i = 0; i < 8; ++i) o[i] = f2bf((xv[i] - mean) * rs * wv8[i] + bv8[i]);
  *(short8v*)(out + (size_t)row * C + tid * 8) = o;
}

// ---------------- GEMM: C[M][N] = A[M][K](bf16) * Bw[N][K](bf16)^T ----------------
// m97 structure: global_load_lds width=16 for BOTH operands.
// EPI: 0 = store bf16, 1 = store f32 (resid + acc), 2 = exact GELU -> bf16
template <int EPI>
__global__ __launch_bounds__(256) void gemm_bt(const short* __restrict__ A,
                                               const short* __restrict__ Bw,
                                               void* __restrict__ Cout,
                                               const float* __restrict__ resid,
                                               int N, int K) {
  __shared__ short As[128 * 64];
  __shared__ short Bs[128 * 64];
  const int tid = threadIdx.x;
  const int lane = tid & 63;
  const int w = tid >> 6;
  const int wr = w >> 1, wc = w & 1;
  const int m0 = blockIdx.y * 128;
  const int n0 = blockIdx.x * 128;

  f32x4 acc[4][4] = {};

  const int sr = lane >> 3;
  const int sc = (lane & 7) * 8;
  const int l15 = lane & 15;
  const int lg = lane >> 4;

  for (int k0 = 0; k0 < K; k0 += 64) {
    __syncthreads();
#pragma unroll
    for (int j = 0; j < 4; ++j) {
      const int r0 = (j * 4 + w) * 8;
      gload_lds16(A + (size_t)(m0 + r0 + sr) * K + k0 + sc, As + r0 * 64);
    }
#pragma unroll
    for (int j = 0; j < 4; ++j) {
      const int r0 = (j * 4 + w) * 8;
      gload_lds16(Bw + (size_t)(n0 + r0 + sr) * K + k0 + sc, Bs + r0 * 64);
    }
    __syncthreads();
#pragma unroll
    for (int kk = 0; kk < 64; kk += 32) {
      bf16x8 af[4], bfr[4];
#pragma unroll
      for (int m = 0; m < 4; ++m)
        af[m] = *(const bf16x8*)(As + (wr * 64 + m * 16 + l15) * 64 + kk + lg * 8);
#pragma unroll
      for (int n = 0; n < 4; ++n)
        bfr[n] = *(const bf16x8*)(Bs + (wc * 64 + n * 16 + l15) * 64 + kk + lg * 8);
#pragma unroll
      for (int m = 0; m < 4; ++m)
#pragma unroll
        for (int n = 0; n < 4; ++n)
          acc[m][n] = __builtin_amdgcn_mfma_f32_16x16x32_bf16(af[m], bfr[n], acc[m][n], 0, 0, 0);
    }
  }

  const int rl = lg * 4;
#pragma unroll
  for (int m = 0; m < 4; ++m) {
#pragma unroll
    for (int n = 0; n < 4; ++n) {
#pragma unroll
      for (int r = 0; r < 4; ++r) {
        const size_t idx = (size_t)(m0 + wr * 64 + m * 16 + rl + r) * N + (n0 + wc * 64 + n * 16 + l15);
        const float v = acc[m][n][r];
        if (EPI == 0) {
          ((short*)Cout)[idx] = f2bf(v);
        } else if (EPI == 1) {
          ((float*)Cout)[idx] = resid[idx] + v;
        } else {
          const float gl = 0.5f * v * (1.f + erff(v * 0.70710678118f));
          ((short*)Cout)[idx] = f2bf(gl);
        }
      }
    }
  }
}

// ---------------- RoPE + [B,T,3,H,D] -> 3x [B,H,T,D] ----------------
__global__ __launch_bounds__(256) void rope_kernel(const short* __restrict__ qkv,
                                                   short* __restrict__ qo,
                                                   short* __restrict__ ko,
                                                   short* __restrict__ vo,
                                                   const int* __restrict__ offset) {
  const int T = 1024, H = 32;
  const int g = blockIdx.x * 256 + threadIdx.x;
  const int j = g & 31;
  const int h = (g >> 5) & 31;
  const int t = (g >> 10) & 1023;
  const int b = g >> 20;
  const size_t inb = (size_t)(b * T + t) * 6144 + h * 64 + 2 * j;
  const size_t outb = (size_t)((b * H + h) * T + t) * 64 + 2 * j;
  const int pos = offset[b] + t;
  const float ang = (float)pos * __builtin_exp2f(-13.287712379549449f * (float)j * (1.f / 32.f));
  float sn, c;
  __sincosf(ang, &sn, &c);
  const float qr = bf2f(qkv[inb]), qi = bf2f(qkv[inb + 1]);
  qo[outb] = f2bf(qr * c - qi * sn);
  qo[outb + 1] = f2bf(qr * sn + qi * c);
  const float kr = bf2f(qkv[inb + 2048]), ki = bf2f(qkv[inb + 2048 + 1]);
  ko[outb] = f2bf(kr * c - ki * sn);
  ko[outb + 1] = f2bf(kr * sn + ki * c);
  vo[outb] = qkv[inb + 4096];
  vo[outb + 1] = qkv[inb + 4096 + 1];
}

// ---------------- Flash attention, sliding-window causal ----------------
__global__ __launch_bounds__(256) void attn_kernel(const short* __restrict__ qb,
                                                   const short* __restrict__ kb,
                                                   const short* __restrict__ vb,
                                                   short* __restrict__ o,
                                                   const int* __restrict__ offset,
                                                   const int* __restrict__ end_offset,
                                                   const int* __restrict__ ctxp) {
  const int T = 1024;
  __shared__ short Ks[64 * 64];
  __shared__ short Vt[64 * 64];
  __shared__ short Ps[4][16 * 64];
  const int tid = threadIdx.x;
  const int lane = tid & 63;
  const int w = tid >> 6;
  const int blk = blockIdx.x;
  const int qt = blk & 15;
  const int bh = blk >> 4;
  const int b = bh >> 5;
  const int h = bh & 31;
  const int q0 = qt * 64;
  const int offq = offset[b];
  const int offk = end_offset[b];
  const int W = ctxp[0];
  const int odelta = offq - offk;

  const short* qp = qb + (size_t)bh * T * 64;
  const short* kp = kb + (size_t)bh * T * 64;
  const short* vp = vb + (size_t)bh * T * 64;

  const int l15 = lane & 15;
  const int lg = lane >> 4;

  bf16x8 qf[2];
  {
    const int qrow = q0 + w * 16 + l15;
    qf[0] = *(const bf16x8*)(qp + (size_t)qrow * 64 + lg * 8);
    qf[1] = *(const bf16x8*)(qp + (size_t)qrow * 64 + 32 + lg * 8);
  }

  f32x4 oacc[4] = {};
  float mrow[4] = {-1e30f, -1e30f, -1e30f, -1e30f};
  float ssum[4] = {0.f, 0.f, 0.f, 0.f};

  int kv_lo = q0 + odelta - (W - 1);
  if (kv_lo < 0) kv_lo = 0;
  int kv_hi = q0 + 63 + odelta;
  if (kv_hi > T - 1) kv_hi = T - 1;

  for (int t0 = (kv_lo & ~63); t0 <= kv_hi; t0 += 64) {
    __syncthreads();
#pragma unroll
    for (int j = 0; j < 2; ++j) {
      const int r0 = (j * 4 + w) * 8;
      gload_lds16(kp + (size_t)(t0 + r0 + (lane >> 3)) * 64 + (lane & 7) * 8, Ks + r0 * 64);
    }
#pragma unroll
    for (int j = 0; j < 2; ++j) {
      const int kv = (tid >> 3) + j * 32;
      const int d0 = (tid & 7) * 8;
      bf16x8 vv = *(const bf16x8*)(vp + (size_t)(t0 + kv) * 64 + d0);
#pragma unroll
      for (int i = 0; i < 8; ++i) Vt[(d0 + i) * 64 + kv] = vv[i];
    }
    __syncthreads();

    f32x4 s[4] = {};
#pragma unroll
    for (int n = 0; n < 4; ++n) {
      bf16x8 k0f = *(const bf16x8*)(Ks + (n * 16 + l15) * 64 + lg * 8);
      bf16x8 k1f = *(const bf16x8*)(Ks + (n * 16 + l15) * 64 + 32 + lg * 8);
      s[n] = __builtin_amdgcn_mfma_f32_16x16x32_bf16(qf[0], k0f, s[n], 0, 0, 0);
      s[n] = __builtin_amdgcn_mfma_f32_16x16x32_bf16(qf[1], k1f, s[n], 0, 0, 0);
    }

#pragma unroll
    for (int r = 0; r < 4; ++r) {
      const int tq = q0 + w * 16 + lg * 4 + r;
      float sv[4];
      float mx = -1e30f;
#pragma unroll
      for (int n = 0; n < 4; ++n) {
        const int tk = t0 + n * 16 + l15;
        const int dd = tq + odelta - tk;
        const bool valid = (dd >= 0) && (dd < W);
        sv[n] = valid ? s[n][r] * 0.125f : -1e30f;
        mx = fmaxf(mx, sv[n]);
      }
      mx = fmaxf(mx, __shfl_xor(mx, 1));
      mx = fmaxf(mx, __shfl_xor(mx, 2));
      mx = fmaxf(mx, __shfl_xor(mx, 4));
      mx = fmaxf(mx, __shfl_xor(mx, 8));
      const float mnew = fmaxf(mrow[r], mx);
      const float sf = __expf(mrow[r] - mnew);
      mrow[r] = mnew;
      float ls = 0.f;
#pragma unroll
      for (int n = 0; n < 4; ++n) {
        const float p = (sv[n] > -0.5e30f) ? __expf(sv[n] - mnew) : 0.f;
        ls += p;
        Ps[w][(lg * 4 + r) * 64 + n * 16 + l15] = f2bf(p);
      }
      ls += __shfl_xor(ls, 1);
      ls += __shfl_xor(ls, 2);
      ls += __shfl_xor(ls, 4);
      ls += __shfl_xor(ls, 8);
      ssum[r] = ssum[r] * sf + ls;
#pragma unroll
      for (int n = 0; n < 4; ++n) oacc[n][r] *= sf;
    }

#pragma unroll
    for (int ks = 0; ks < 2; ++ks) {
      bf16x8 pa = *(const bf16x8*)(&Ps[w][l15 * 64 + ks * 32 + lg * 8]);
#pragma unroll
      for (int n = 0; n < 4; ++n) {
        bf16x8 vf = *(const bf16x8*)(Vt + (n * 16 + l15) * 64 + ks * 32 + lg * 8);
        oacc[n] = __builtin_amdgcn_mfma_f32_16x16x32_bf16(pa, vf, oacc[n], 0, 0, 0);
      }
    }
  }

#pragma unroll
  for (int n = 0; n < 4; ++n) {
#pragma unroll
    for (int r = 0; r < 4; ++r) {
      const int tq = q0 + w * 16 + lg * 4 + r;
      const float val = oacc[n][r] / ssum[r];
      o[(size_t)(b * T + tq) * 2048 + h * 64 + n * 16 + l15] = f2bf(val);
    }
  }
}

extern "C" void kernel_launch(void* const* d_in, const int* in_sizes, int n_in,
                              void* d_out, int out_size, void* d_ws, size_t ws_size,
                              hipStream_t stream) {
  (void)in_sizes; (void)n_in; (void)out_size; (void)ws_size;
  const float* x          = (const float*)d_in[0];
  const float* in_proj_w  = (const float*)d_in[2];
  const float* out_proj_w = (const float*)d_in[3];
  const float* ln1_w      = (const float*)d_in[4];
  const float* ln1_b      = (const float*)d_in[5];
  const float* ln2_w      = (const float*)d_in[6];
  const float* ln2_b      = (const float*)d_in[7];
  const float* lin1_w     = (const float*)d_in[8];
  const float* lin2_w     = (const float*)d_in[9];
  const int* offset       = (const int*)d_in[10];
  const int* end_offset   = (const int*)d_in[11];
  const int* ctx          = (const int*)d_in[12];
  float* out = (float*)d_out;

  const size_t MiB = 1048576;
  char* ws = (char*)d_ws;
  // Live-range-packed layout (peak 88 MiB):
  float* x1   = (float*)(ws);               // [0,16)    f32 [2048][2048]
  short* hbuf = (short*)(ws + 16 * MiB);    // [16,24)   bf16 (h -> o -> h2)
  short* qkv  = (short*)(ws + 24 * MiB);    // [24,48)   bf16 [2048][6144]
  short* qr   = (short*)(ws + 48 * MiB);    // [48,56)
  short* kr   = (short*)(ws + 56 * MiB);    // [56,64)
  short* vr   = (short*)(ws + 64 * MiB);    // [64,72)
  short* g    = (short*)(ws + 24 * MiB);    // [24,56)   overlays qkv+qr (dead)
  short* wb_in   = (short*)(ws + 48 * MiB); // [48,72)   overlays qr/kr/vr (not yet live)
  short* wb_out  = (short*)(ws + 24 * MiB); // [24,32)   overlays qkv (dead)
  short* wb_lin  = (short*)(ws + 56 * MiB); // [56,88)   overlays kr/vr (dead) + beyond

  // 1. LN1: x -> h(bf16)
  ln_kernel<<<2048, 256, 0, stream>>>(x, ln1_w, ln1_b, hbuf);
  // 2. QKV = h @ in_proj_w^T  (convert weight first)
  cvt_kernel<<<2048, 256, 0, stream>>>(in_proj_w, wb_in, 12582912 / 8);
  gemm_bt<0><<<dim3(48, 16), 256, 0, stream>>>(hbuf, wb_in, qkv, nullptr, 6144, 2048);
  // 3. RoPE + rearrange to [B,H,T,D]
  rope_kernel<<<8192, 256, 0, stream>>>(qkv, qr, kr, vr, offset);
  // 4. Attention -> o (reuses hbuf) in [B,T,H*D] layout
  attn_kernel<<<1024, 256, 0, stream>>>(qr, kr, vr, hbuf, offset, end_offset, ctx);
  // 5. x1 = x + o @ out_proj_w^T
  cvt_kernel<<<2048, 256, 0, stream>>>(out_proj_w, wb_out, 4194304 / 8);
  gemm_bt<1><<<dim3(16, 16), 256, 0, stream>>>(hbuf, wb_out, x1, x, 2048, 2048);
  // 6. LN2: x1 -> h2 (reuses hbuf)
  ln_kernel<<<2048, 256, 0, stream>>>(x1, ln2_w, ln2_b, hbuf);
  // 7. g = gelu(h2 @ lin1_w^T)
  cvt_kernel<<<2048, 256, 0, stream>>>(lin1_w, wb_lin, 16777216 / 8);
  gemm_bt<2><<<dim3(64, 16), 256, 0, stream>>>(hbuf, wb_lin, g, nullptr, 8192, 2048);
  // 8. out = x1 + g @ lin2_w^T
  cvt_kernel<<<2048, 256, 0, stream>>>(lin2_w, wb_lin, 16777216 / 8);
  gemm_bt<1><<<dim3(16, 16), 256, 0, stream>>>(g, wb_lin, out, x1, 2048, 8192);
}

// Round 3
// 432.627 us; speedup vs baseline: 1.5141x; 1.2812x over previous
//
#include <hip/hip_runtime.h>

typedef __attribute__((ext_vector_type(8))) short bf16x8;
typedef __attribute__((ext_vector_type(4))) float f32x4;
typedef __attribute__((ext_vector_type(8))) short short8v;
typedef __attribute__((ext_vector_type(4))) float float4v;

#define DEV static __device__ __forceinline__

DEV short f2bf(float f) {
  unsigned u = __builtin_bit_cast(unsigned, f);
  u = (u + 0x7fffu + ((u >> 16) & 1u)) >> 16;
  return (short)u;
}
DEV float bf2f(short s) {
  unsigned u = ((unsigned)(unsigned short)s) << 16;
  return __builtin_bit_cast(float, u);
}

DEV void gload_lds16(const void* g, void* l) {
  __builtin_amdgcn_global_load_lds((const __attribute__((address_space(1))) void*)g,
                                   (__attribute__((address_space(3))) void*)l, 16, 0, 0);
}

// ---------------- f32 -> bf16 convert ----------------
__global__ __launch_bounds__(256) void cvt_kernel(const float* __restrict__ src,
                                                  short* __restrict__ dst, int n8) {
  int i = blockIdx.x * 256 + threadIdx.x;
  const int stride = gridDim.x * 256;
  for (; i < n8; i += stride) {
    float4v a = ((const float4v*)src)[i * 2];
    float4v b = ((const float4v*)src)[i * 2 + 1];
    short8v o;
    o[0] = f2bf(a.x); o[1] = f2bf(a.y); o[2] = f2bf(a.z); o[3] = f2bf(a.w);
    o[4] = f2bf(b.x); o[5] = f2bf(b.y); o[6] = f2bf(b.z); o[7] = f2bf(b.w);
    ((short8v*)dst)[i] = o;
  }
}

// ---------------- LayerNorm: f32 [rows][2048] -> bf16 ----------------
__global__ __launch_bounds__(256) void ln_kernel(const float* __restrict__ x,
                                                 const float* __restrict__ w,
                                                 const float* __restrict__ b,
                                                 short* __restrict__ out) {
  const int C = 2048;
  const int row = blockIdx.x;
  const int tid = threadIdx.x;
  const float* xr = x + (size_t)row * C;
  float xv[8];
  *(float4v*)(xv) = *(const float4v*)(xr + tid * 8);
  *(float4v*)(xv + 4) = *(const float4v*)(xr + tid * 8 + 4);
  float s = 0.f, ss = 0.f;
#pragma unroll
  for (int i = 0; i < 8; ++i) { s += xv[i]; ss += xv[i] * xv[i]; }
#pragma unroll
  for (int d = 1; d < 64; d <<= 1) { s += __shfl_xor(s, d); ss += __shfl_xor(ss, d); }
  __shared__ float red[8];
  const int lane = tid & 63, wv = tid >> 6;
  if (lane == 0) { red[wv] = s; red[4 + wv] = ss; }
  __syncthreads();
  s = red[0] + red[1] + red[2] + red[3];
  ss = red[4] + red[5] + red[6] + red[7];
  const float mean = s * (1.f / 2048.f);
  const float var = ss * (1.f / 2048.f) - mean * mean;
  const float rs = rsqrtf(var + 1e-5f);
  float wv8[8], bv8[8];
  *(float4v*)(wv8) = *(const float4v*)(w + tid * 8);
  *(float4v*)(wv8 + 4) = *(const float4v*)(w + tid * 8 + 4);
  *(float4v*)(bv8) = *(const float4v*)(b + tid * 8);
  *(float4v*)(bv8 + 4) = *(const float4v*)(b + tid * 8 + 4);
  short8v o;
#pragma unroll
  for (int i = 0; i < 8; ++i) o[i] = f2bf((xv[i] - mean) * rs * wv8[i] + bv8[i]);
  *(short8v*)(out + (size_t)row * C + tid * 8) = o;
}

// ================= 256x256 GEMM, BK=32, depth-3 counted-vmcnt pipeline =================
// C[M][N] = A[M][K](bf16) * Bw[N][K](bf16)^T, K-chunk per blockIdx.z.
// 8 waves (2Mx4N), per-wave 128x64 output, acc[8][4]. LDS: 4 bufs x (A 16KB + B 16KB).
// Wait ledger: stages for tiles t..t+2 in flight (4 loads each) -> vmcnt(8) at tile t
// retires exactly tile t's loads; barrier broadcasts; then stage t+3 into buf (t+3)&3,
// which all waves finished reading (as tile t-1) before this barrier.
// Swizzle (T2): 16B-slot ^= (row>>1)&3 within 64B row; applied to stage SOURCE and read.
// EPI: 0 = bf16 store, 2 = exact GELU -> bf16, 3 = raw f32 store (split-K partial)
template <int EPI>
__global__ __launch_bounds__(512, 2) void gemm256(const short* __restrict__ A,
                                                  const short* __restrict__ Bw,
                                                  void* __restrict__ C0, void* __restrict__ C1,
                                                  void* __restrict__ C2, void* __restrict__ C3,
                                                  int N, int K, int kChunk, int kTiles) {
  extern __shared__ short smem[];  // 65536 shorts = 128 KiB
  const int tid = threadIdx.x;
  const int lane = tid & 63;
  const int wv = tid >> 6;
  const int wr = wv >> 2;       // 0..1
  const int wc = wv & 3;        // 0..3
  const int m0 = blockIdx.y * 256;
  const int n0 = blockIdx.x * 256;
  const int kBegin = blockIdx.z * kChunk;

  const int l15 = lane & 15;
  const int lg = lane >> 4;

  // staging geometry: flat f in [0,1024): row = f>>2, 16B slot = f&3 (row = 32 bf16 = 64B)
  const int fa0 = tid, fa1 = tid + 512;
  const int rA0 = fa0 >> 2, rA1 = fa1 >> 2;
  const int cA0 = (((fa0 & 3) ^ ((rA0 >> 1) & 3))) * 8;  // swizzled source col (elems)
  const int cA1 = (((fa1 & 3) ^ ((rA1 >> 1) & 3))) * 8;

  const short* Asrc0 = A + (size_t)(m0 + rA0) * K + kBegin + cA0;
  const short* Asrc1 = A + (size_t)(m0 + rA1) * K + kBegin + cA1;
  const short* Bsrc0 = Bw + (size_t)(n0 + rA0) * K + kBegin + cA0;
  const short* Bsrc1 = Bw + (size_t)(n0 + rA1) * K + kBegin + cA1;

  f32x4 acc[8][4] = {};

#define STAGE(t)                                                        \
  {                                                                     \
    short* dstb = smem + (((t) & 3) * 16384);                           \
    const size_t ko = (size_t)(t) * 32;                                 \
    gload_lds16(Asrc0 + ko, dstb + fa0 * 8);                            \
    gload_lds16(Asrc1 + ko, dstb + fa1 * 8);                            \
    gload_lds16(Bsrc0 + ko, dstb + 8192 + fa0 * 8);                     \
    gload_lds16(Bsrc1 + ko, dstb + 8192 + fa1 * 8);                     \
  }

  // prologue: stage tiles 0..2
  const int pre = kTiles < 3 ? kTiles : 3;
  for (int p = 0; p < pre; ++p) STAGE(p);

  for (int t = 0; t < kTiles; ++t) {
    const int rem = kTiles - 1 - t;
    if (rem >= 2) {
      asm volatile("s_waitcnt vmcnt(8)" ::: "memory");
    } else if (rem == 1) {
      asm volatile("s_waitcnt vmcnt(4)" ::: "memory");
    } else {
      asm volatile("s_waitcnt vmcnt(0)" ::: "memory");
    }
    __builtin_amdgcn_sched_barrier(0);
    __builtin_amdgcn_s_barrier();
    __builtin_amdgcn_sched_barrier(0);

    if (t + 3 < kTiles) STAGE(t + 3);

    const short* sa = smem + ((t & 3) * 16384);
    const short* sb = sa + 8192;
    bf16x8 af[8], bf[4];
#pragma unroll
    for (int m = 0; m < 8; ++m) {
      const int row = wr * 128 + m * 16 + l15;
      af[m] = *(const bf16x8*)(sa + row * 32 + ((lg ^ ((row >> 1) & 3)) * 8));
    }
#pragma unroll
    for (int n = 0; n < 4; ++n) {
      const int row = wc * 64 + n * 16 + l15;
      bf[n] = *(const bf16x8*)(sb + row * 32 + ((lg ^ ((row >> 1) & 3)) * 8));
    }
    __builtin_amdgcn_s_setprio(1);
#pragma unroll
    for (int m = 0; m < 8; ++m)
#pragma unroll
      for (int n = 0; n < 4; ++n)
        acc[m][n] = __builtin_amdgcn_mfma_f32_16x16x32_bf16(af[m], bf[n], acc[m][n], 0, 0, 0);
    __builtin_amdgcn_s_setprio(0);
  }
#undef STAGE

  void* Cout = blockIdx.z == 0 ? C0 : blockIdx.z == 1 ? C1 : blockIdx.z == 2 ? C2 : C3;
#pragma unroll
  for (int m = 0; m < 8; ++m) {
#pragma unroll
    for (int n = 0; n < 4; ++n) {
#pragma unroll
      for (int r = 0; r < 4; ++r) {
        const size_t idx =
            (size_t)(m0 + wr * 128 + m * 16 + lg * 4 + r) * N + (n0 + wc * 64 + n * 16 + l15);
        const float v = acc[m][n][r];
        if (EPI == 0) {
          ((short*)Cout)[idx] = f2bf(v);
        } else if (EPI == 2) {
          const float gl = 0.5f * v * (1.f + erff(v * 0.70710678118f));
          ((short*)Cout)[idx] = f2bf(gl);
        } else {
          ((float*)Cout)[idx] = v;
        }
      }
    }
  }
}

// ---------------- split-K reduce: dst = resid + dst + p1 (+ p2 + p3) ----------------
__global__ __launch_bounds__(256) void reduce_k(float* __restrict__ dst,
                                                const float* __restrict__ resid,
                                                const float* __restrict__ p1,
                                                const float* __restrict__ p2,
                                                const float* __restrict__ p3,
                                                int ns, int n4) {
  int i = blockIdx.x * 256 + threadIdx.x;
  const int stride = gridDim.x * 256;
  for (; i < n4; i += stride) {
    float4v d = ((const float4v*)dst)[i];
    float4v r = ((const float4v*)resid)[i];
    float4v a = ((const float4v*)p1)[i];
    d.x += r.x + a.x; d.y += r.y + a.y; d.z += r.z + a.z; d.w += r.w + a.w;
    if (ns == 4) {
      float4v b = ((const float4v*)p2)[i];
      float4v c = ((const float4v*)p3)[i];
      d.x += b.x + c.x; d.y += b.y + c.y; d.z += b.z + c.z; d.w += b.w + c.w;
    }
    ((float4v*)dst)[i] = d;
  }
}

// ---------------- RoPE + [B,T,3,H,D] -> 3x [B,H,T,D] ----------------
__global__ __launch_bounds__(256) void rope_kernel(const short* __restrict__ qkv,
                                                   short* __restrict__ qo,
                                                   short* __restrict__ ko,
                                                   short* __restrict__ vo,
                                                   const int* __restrict__ offset) {
  const int T = 1024, H = 32;
  const int g = blockIdx.x * 256 + threadIdx.x;
  const int j = g & 31;
  const int h = (g >> 5) & 31;
  const int t = (g >> 10) & 1023;
  const int b = g >> 20;
  const size_t inb = (size_t)(b * T + t) * 6144 + h * 64 + 2 * j;
  const size_t outb = (size_t)((b * H + h) * T + t) * 64 + 2 * j;
  const int pos = offset[b] + t;
  const float ang = (float)pos * __builtin_exp2f(-13.287712379549449f * (float)j * (1.f / 32.f));
  float sn, c;
  __sincosf(ang, &sn, &c);
  const float qr = bf2f(qkv[inb]), qi = bf2f(qkv[inb + 1]);
  qo[outb] = f2bf(qr * c - qi * sn);
  qo[outb + 1] = f2bf(qr * sn + qi * c);
  const float kr = bf2f(qkv[inb + 2048]), ki = bf2f(qkv[inb + 2048 + 1]);
  ko[outb] = f2bf(kr * c - ki * sn);
  ko[outb + 1] = f2bf(kr * sn + ki * c);
  vo[outb] = qkv[inb + 4096];
  vo[outb + 1] = qkv[inb + 4096 + 1];
}

// ---------------- Flash attention, sliding-window causal ----------------
__global__ __launch_bounds__(256) void attn_kernel(const short* __restrict__ qb,
                                                   const short* __restrict__ kb,
                                                   const short* __restrict__ vb,
                                                   short* __restrict__ o,
                                                   const int* __restrict__ offset,
                                                   const int* __restrict__ end_offset,
                                                   const int* __restrict__ ctxp) {
  const int T = 1024;
  __shared__ short Ks[64 * 64];
  __shared__ short Vt[64 * 64];
  __shared__ short Ps[4][16 * 64];
  const int tid = threadIdx.x;
  const int lane = tid & 63;
  const int w = tid >> 6;
  const int blk = blockIdx.x;
  const int qt = blk & 15;
  const int bh = blk >> 4;
  const int b = bh >> 5;
  const int h = bh & 31;
  const int q0 = qt * 64;
  const int offq = offset[b];
  const int offk = end_offset[b];
  const int W = ctxp[0];
  const int odelta = offq - offk;

  const short* qp = qb + (size_t)bh * T * 64;
  const short* kp = kb + (size_t)bh * T * 64;
  const short* vp = vb + (size_t)bh * T * 64;

  const int l15 = lane & 15;
  const int lg = lane >> 4;

  bf16x8 qf[2];
  {
    const int qrow = q0 + w * 16 + l15;
    qf[0] = *(const bf16x8*)(qp + (size_t)qrow * 64 + lg * 8);
    qf[1] = *(const bf16x8*)(qp + (size_t)qrow * 64 + 32 + lg * 8);
  }

  f32x4 oacc[4] = {};
  float mrow[4] = {-1e30f, -1e30f, -1e30f, -1e30f};
  float ssum[4] = {0.f, 0.f, 0.f, 0.f};

  int kv_lo = q0 + odelta - (W - 1);
  if (kv_lo < 0) kv_lo = 0;
  int kv_hi = q0 + 63 + odelta;
  if (kv_hi > T - 1) kv_hi = T - 1;

  for (int t0 = (kv_lo & ~63); t0 <= kv_hi; t0 += 64) {
    __syncthreads();
#pragma unroll
    for (int j = 0; j < 2; ++j) {
      const int r0 = (j * 4 + w) * 8;
      gload_lds16(kp + (size_t)(t0 + r0 + (lane >> 3)) * 64 + (lane & 7) * 8, Ks + r0 * 64);
    }
#pragma unroll
    for (int j = 0; j < 2; ++j) {
      const int kv = (tid >> 3) + j * 32;
      const int d0 = (tid & 7) * 8;
      bf16x8 vv = *(const bf16x8*)(vp + (size_t)(t0 + kv) * 64 + d0);
#pragma unroll
      for (int i = 0; i < 8; ++i) Vt[(d0 + i) * 64 + kv] = vv[i];
    }
    __syncthreads();

    f32x4 s[4] = {};
#pragma unroll
    for (int n = 0; n < 4; ++n) {
      bf16x8 k0f = *(const bf16x8*)(Ks + (n * 16 + l15) * 64 + lg * 8);
      bf16x8 k1f = *(const bf16x8*)(Ks + (n * 16 + l15) * 64 + 32 + lg * 8);
      s[n] = __builtin_amdgcn_mfma_f32_16x16x32_bf16(qf[0], k0f, s[n], 0, 0, 0);
      s[n] = __builtin_amdgcn_mfma_f32_16x16x32_bf16(qf[1], k1f, s[n], 0, 0, 0);
    }

#pragma unroll
    for (int r = 0; r < 4; ++r) {
      const int tq = q0 + w * 16 + lg * 4 + r;
      float sv[4];
      float mx = -1e30f;
#pragma unroll
      for (int n = 0; n < 4; ++n) {
        const int tk = t0 + n * 16 + l15;
        const int dd = tq + odelta - tk;
        const bool valid = (dd >= 0) && (dd < W);
        sv[n] = valid ? s[n][r] * 0.125f : -1e30f;
        mx = fmaxf(mx, sv[n]);
      }
      mx = fmaxf(mx, __shfl_xor(mx, 1));
      mx = fmaxf(mx, __shfl_xor(mx, 2));
      mx = fmaxf(mx, __shfl_xor(mx, 4));
      mx = fmaxf(mx, __shfl_xor(mx, 8));
      const float mnew = fmaxf(mrow[r], mx);
      const float sf = __expf(mrow[r] - mnew);
      mrow[r] = mnew;
      float ls = 0.f;
#pragma unroll
      for (int n = 0; n < 4; ++n) {
        const float p = (sv[n] > -0.5e30f) ? __expf(sv[n] - mnew) : 0.f;
        ls += p;
        Ps[w][(lg * 4 + r) * 64 + n * 16 + l15] = f2bf(p);
      }
      ls += __shfl_xor(ls, 1);
      ls += __shfl_xor(ls, 2);
      ls += __shfl_xor(ls, 4);
      ls += __shfl_xor(ls, 8);
      ssum[r] = ssum[r] * sf + ls;
#pragma unroll
      for (int n = 0; n < 4; ++n) oacc[n][r] *= sf;
    }

#pragma unroll
    for (int ks = 0; ks < 2; ++ks) {
      bf16x8 pa = *(const bf16x8*)(&Ps[w][l15 * 64 + ks * 32 + lg * 8]);
#pragma unroll
      for (int n = 0; n < 4; ++n) {
        bf16x8 vf = *(const bf16x8*)(Vt + (n * 16 + l15) * 64 + ks * 32 + lg * 8);
        oacc[n] = __builtin_amdgcn_mfma_f32_16x16x32_bf16(pa, vf, oacc[n], 0, 0, 0);
      }
    }
  }

#pragma unroll
  for (int n = 0; n < 4; ++n) {
#pragma unroll
    for (int r = 0; r < 4; ++r) {
      const int tq = q0 + w * 16 + lg * 4 + r;
      const float val = oacc[n][r] / ssum[r];
      o[(size_t)(b * T + tq) * 2048 + h * 64 + n * 16 + l15] = f2bf(val);
    }
  }
}

extern "C" void kernel_launch(void* const* d_in, const int* in_sizes, int n_in,
                              void* d_out, int out_size, void* d_ws, size_t ws_size,
                              hipStream_t stream) {
  (void)in_sizes; (void)n_in; (void)out_size;
  const float* x          = (const float*)d_in[0];
  const float* in_proj_w  = (const float*)d_in[2];
  const float* out_proj_w = (const float*)d_in[3];
  const float* ln1_w      = (const float*)d_in[4];
  const float* ln1_b      = (const float*)d_in[5];
  const float* ln2_w      = (const float*)d_in[6];
  const float* ln2_b      = (const float*)d_in[7];
  const float* lin1_w     = (const float*)d_in[8];
  const float* lin2_w     = (const float*)d_in[9];
  const int* offset       = (const int*)d_in[10];
  const int* end_offset   = (const int*)d_in[11];
  const int* ctx          = (const int*)d_in[12];
  float* out = (float*)d_out;

  hipFuncSetAttribute((const void*)gemm256<0>, hipFuncAttributeMaxDynamicSharedMemorySize, 131072);
  hipFuncSetAttribute((const void*)gemm256<2>, hipFuncAttributeMaxDynamicSharedMemorySize, 131072);
  hipFuncSetAttribute((const void*)gemm256<3>, hipFuncAttributeMaxDynamicSharedMemorySize, 131072);

  const size_t MiB = 1048576;
  char* ws = (char*)d_ws;
  float* x1    = (float*)(ws);                // [0,16)   f32 [2048][2048]
  short* hbuf  = (short*)(ws + 16 * MiB);     // [16,24)  bf16 (h -> o -> h2)
  short* qkv   = (short*)(ws + 24 * MiB);     // [24,48)  bf16 [2048][6144]
  short* qr    = (short*)(ws + 48 * MiB);     // [48,56)
  short* kr    = (short*)(ws + 56 * MiB);     // [56,64)
  short* vr    = (short*)(ws + 64 * MiB);     // [64,72)
  short* wb_in = (short*)(ws + 48 * MiB);     // [48,72)  overlays qr/kr/vr (pre-rope)
  short* wb_out= (short*)(ws + 24 * MiB);     // [24,32)  overlays qkv (dead post-rope)
  float* p1o   = (float*)(ws + 32 * MiB);     // [32,48)  OutProj split-K partial 1
  short* g     = (short*)(ws + 24 * MiB);     // [24,56)  FF1 out (wb_out/p1o/qr dead)
  short* wb1   = (short*)(ws + 64 * MiB);     // [64,80)  lin1 bf16 (vr dead post-attn)
  short* wb2   = (short*)(ws + 56 * MiB);     // [56,72)  lin2 bf16 (kr/vr/wb1 dead)
  float* p1f   = (float*)(ws + 72 * MiB);     // [72,88)  FF2 partial 1
  float* p2f   = (float*)(ws + 88 * MiB);     // [88,104)  (only if ws allows)
  float* p3f   = (float*)(ws + 104 * MiB);    // [104,120)
  const int NS_FF2 = (ws_size >= 121 * MiB) ? 4 : 2;

  // 1. LN1: x -> h(bf16)
  ln_kernel<<<2048, 256, 0, stream>>>(x, ln1_w, ln1_b, hbuf);
  // 2. QKV = h @ in_proj_w^T
  cvt_kernel<<<2048, 256, 0, stream>>>(in_proj_w, wb_in, 12582912 / 8);
  gemm256<0><<<dim3(24, 8, 1), 512, 131072, stream>>>(hbuf, wb_in, qkv, nullptr, nullptr, nullptr,
                                                      6144, 2048, 2048, 64);
  // 3. RoPE + rearrange to [B,H,T,D]
  rope_kernel<<<8192, 256, 0, stream>>>(qkv, qr, kr, vr, offset);
  // 4. Attention -> o (reuses hbuf) in [B,T,H*D] layout
  attn_kernel<<<1024, 256, 0, stream>>>(qr, kr, vr, hbuf, offset, end_offset, ctx);
  // 5. x1 = x + o @ out_proj_w^T  (split-K 2: partial0 -> x1, partial1 -> p1o)
  cvt_kernel<<<2048, 256, 0, stream>>>(out_proj_w, wb_out, 4194304 / 8);
  gemm256<3><<<dim3(8, 8, 2), 512, 131072, stream>>>(hbuf, wb_out, x1, p1o, nullptr, nullptr,
                                                     2048, 2048, 1024, 32);
  reduce_k<<<1024, 256, 0, stream>>>(x1, x, p1o, nullptr, nullptr, 2, 1048576);
  // 6. LN2: x1 -> h2 (reuses hbuf)
  ln_kernel<<<2048, 256, 0, stream>>>(x1, ln2_w, ln2_b, hbuf);
  // 7. g = gelu(h2 @ lin1_w^T)
  cvt_kernel<<<2048, 256, 0, stream>>>(lin1_w, wb1, 16777216 / 8);
  gemm256<2><<<dim3(32, 8, 1), 512, 131072, stream>>>(hbuf, wb1, g, nullptr, nullptr, nullptr,
                                                      8192, 2048, 2048, 64);
  // 8. out = x1 + g @ lin2_w^T  (split-K: partial0 -> out, rest -> p1f..p3f)
  cvt_kernel<<<2048, 256, 0, stream>>>(lin2_w, wb2, 16777216 / 8);
  if (NS_FF2 == 4) {
    gemm256<3><<<dim3(8, 8, 4), 512, 131072, stream>>>(g, wb2, out, p1f, p2f, p3f,
                                                       2048, 8192, 2048, 64);
    reduce_k<<<1024, 256, 0, stream>>>(out, x1, p1f, p2f, p3f, 4, 1048576);
  } else {
    gemm256<3><<<dim3(8, 8, 2), 512, 131072, stream>>>(g, wb2, out, p1f, nullptr, nullptr,
                                                       2048, 8192, 4096, 128);
    reduce_k<<<1024, 256, 0, stream>>>(out, x1, p1f, nullptr, nullptr, 2, 1048576);
  }
}